// Round 12
// baseline (403.797 us; speedup 1.0000x reference)
//
#include <hip/hip_runtime.h>

#define T 64
#define F_IN 3
#define H 16
#define G 48
#define D2 32
#define DEPTH 5
#define NCLS 4
#define L2E 1.44269504f

// LDS geometry (f16 element units)
#define YST 32          // f16 per t-row (64 B rows)
#define YSB 2048        // f16 per batch elem
#define HZ_ZOFF 64      // zero block inside hzb (16 B)

typedef _Float16 half8 __attribute__((ext_vector_type(8)));
typedef float f32x4v __attribute__((ext_vector_type(4)));

__device__ __forceinline__ float fexp2(float x) { return __builtin_amdgcn_exp2f(x); }
__device__ __forceinline__ float frcp(float x)  { return __builtin_amdgcn_rcpf(x); }

// One wave per WG, 4 jobs: job = quad, lb = quad&1, dir = quad>>1.
// All gate pre-activations carry log2(e) folded into weights/biases (raw
// v_exp_f32); n-gate additionally scaled by -2 (R9 fused tanh+blend).
// gx (R11): K-split MFMA chain per gate (fwd k<16 / bwd k>=16, bwd t-mirrored
// so C reg s == step s, zero per-step selects). Biases ride in C operands.
// gh: per step, 1 ds_read_b128 of h + 3 MFMAs (direction split in K-space).
// R12: launch_bounds(64,4). R11's measured VGPR=84 fits the 128-reg budget
// (R6/R7 spill was the OLD structure at ~135 regs). 4 waves/SIMD fills the
// ~617-cyc per-step latency chain (R11 model: 2.42 waves -> VALUBusy 63%).
// Single wave per WG => lockstep => no __syncthreads() anywhere.
__global__ __launch_bounds__(64, 4) void bigru_all(
    const float* __restrict__ x,
    const float* __restrict__ Wi1, const float* __restrict__ Wh1,
    const float* __restrict__ bi1, const float* __restrict__ bh1,
    const float* __restrict__ Wi5, const float* __restrict__ Wh5,
    const float* __restrict__ bi5, const float* __restrict__ bh5,
    const float* __restrict__ Wc,  const float* __restrict__ bc,
    float* __restrict__ out)
{
    __shared__ __align__(16) _Float16 yb[2 * YSB];
    __shared__ __align__(16) _Float16 hzb[80];     // [0,64): h[job][16]; [64,72): zeros

    const int lane = threadIdx.x;
    const int j15  = lane & 15;
    const int quad = lane >> 4;
    const int lb   = quad & 1;
    const int dir  = quad >> 1;
    const bool isf = (dir == 0);

    hzb[lane] = (_Float16)0.0f;
    if (lane < 16) hzb[64 + lane] = (_Float16)0.0f;

    // gh A-frag source (loop-invariant)
    const int  job_a  = j15 >> 2;
    const bool avalid = ((j15 >> 3) == 0) ? (quad < 2) : (quad >= 2);
    const _Float16* aptr = hzb + (avalid ? (job_a * 16 + (quad & 1) * 8) : HZ_ZOFF);

    const int ystep = isf ? YST : -YST;
    const f32x4v zC = {0.f, 0.f, 0.f, 0.f};
    const int klo = (quad & 1) * 8;        // k-offset within a 16-dim half
    const int bdir = (quad < 2) ? 0 : 1;   // which dir's weights this lane's B/A k-half serves

    float hj;

    // ================= layer 1 (gx scalar from global x, gh via MFMA) =======
    {
        half8 whB[3];
        {
            const float* wsrc = Wh1 + bdir * (G * H);
            #pragma unroll
            for (int g = 0; g < 3; ++g) {
                const float scale = (g == 2) ? (-2.0f * L2E) : L2E;
                const float* w = wsrc + (g * 16 + j15) * H + klo;
                half8 hv;
                #pragma unroll
                for (int i = 0; i < 8; ++i) hv[i] = (_Float16)(scale * w[i]);
                whB[g] = hv;
            }
        }
        float wi[3][F_IN];
        float bir[3], bhn2;
        {
            const float* Wi = Wi1 + dir * (G * F_IN);
            const float* bi = bi1 + dir * G;
            const float* bh = bh1 + dir * G;
            #pragma unroll
            for (int g = 0; g < 3; ++g) {
                const float scale = (g == 2) ? (-2.0f * L2E) : L2E;
                int row = g * H + j15;
                #pragma unroll
                for (int k = 0; k < F_IN; ++k) wi[g][k] = scale * Wi[row * F_IN + k];
                bir[g] = scale * bi[row] + ((g < 2) ? (L2E * bh[row]) : 0.0f);
            }
            bhn2 = -2.0f * L2E * bh[2 * H + j15];
        }
        const f32x4v cN = {bhn2, bhn2, bhn2, bhn2};
        hj = 0.0f;

        const float* xg = x + (size_t)blockIdx.x * (2 * T * F_IN) + (size_t)lb * (T * F_IN);
        _Float16* yw = yb + lb * YSB + (isf ? 0 : (T - 1)) * YST + dir * H + j15;

        #pragma unroll 4
        for (int s = 0; s < T; ++s) {
            int t = isf ? s : (T - 1 - s);
            const float* xp = xg + t * F_IN;
            float x0 = xp[0], x1 = xp[1], x2 = xp[2];
            float gxr = fmaf(wi[0][2], x2, fmaf(wi[0][1], x1, fmaf(wi[0][0], x0, bir[0])));
            float gxz = fmaf(wi[1][2], x2, fmaf(wi[1][1], x1, fmaf(wi[1][0], x0, bir[1])));
            float gxn = fmaf(wi[2][2], x2, fmaf(wi[2][1], x1, fmaf(wi[2][0], x0, bir[2])));
            half8 a = *(const half8*)aptr;
            f32x4v d0 = __builtin_amdgcn_mfma_f32_16x16x32_f16(a, whB[0], zC, 0, 0, 0);
            f32x4v d1 = __builtin_amdgcn_mfma_f32_16x16x32_f16(a, whB[1], zC, 0, 0, 0);
            f32x4v d2 = __builtin_amdgcn_mfma_f32_16x16x32_f16(a, whB[2], cN, 0, 0, 0);
            float av = gxr + d0[0];
            float bv = gxz + d1[0];
            float Er = fexp2(fminf(58.f, -av));
            float rg = frcp(1.0f + Er);
            float c2 = fmaf(rg, d2[0], gxn);           // = -2c*log2e
            float Ez = fexp2(fminf(58.f, -bv));
            float Ec = fexp2(fminf(63.f, c2));
            float num = fmaf(hj - Ez, Ec, hj + Ez);
            float den = (1.0f + Ec) * (1.0f + Ez);
            float hn = num * frcp(den);
            hj = hn;
            _Float16 hh = (_Float16)hn;
            hzb[lane] = hh;
            *yw = hh;
            yw += ystep;
        }
    }

    // ================= layers 2..6 =================
    #pragma unroll 1
    for (int l = 0; l < DEPTH; ++l) {
        // gx B-frags, K-split: this lane's k-half serves dir=bdir
        half8 bflo[3], bfhi[3];
        #pragma unroll
        for (int g = 0; g < 3; ++g) {
            const float scale = (g == 2) ? (-2.0f * L2E) : L2E;
            const float* w = Wi5 + ((size_t)(l * 2 + bdir) * G + g * 16 + j15) * D2;
            half8 lo, hi;
            #pragma unroll
            for (int i = 0; i < 8; ++i) {
                lo[i] = (_Float16)(scale * w[klo + i]);
                hi[i] = (_Float16)(scale * w[16 + klo + i]);
            }
            bflo[g] = lo;
            bfhi[g] = hi;
        }
        // gh B-frags (dir split by quad-half)
        half8 whB[3];
        {
            const float* wsrc = Wh5 + ((size_t)(l * 2) + bdir) * G * H;
            #pragma unroll
            for (int g = 0; g < 3; ++g) {
                const float scale = (g == 2) ? (-2.0f * L2E) : L2E;
                const float* w = wsrc + (g * 16 + j15) * H + klo;
                half8 hv;
                #pragma unroll
                for (int i = 0; i < 8; ++i) hv[i] = (_Float16)(scale * w[i]);
                whB[g] = hv;
            }
        }
        // own-dir biases -> C splats (scaled)
        float bib0, bib1, bib2, bhn2;
        {
            const float* biL = bi5 + (l * 2 + dir) * G;
            const float* bhL = bh5 + (l * 2 + dir) * G;
            bib0 = L2E * (biL[j15]     + bhL[j15]);
            bib1 = L2E * (biL[H + j15] + bhL[H + j15]);
            bib2 = -2.0f * L2E * biL[2 * H + j15];
            bhn2 = -2.0f * L2E * bhL[2 * H + j15];
        }
        const f32x4v cR  = {bib0, bib0, bib0, bib0};
        const f32x4v cZ  = {bib1, bib1, bib1, bib1};
        const f32x4v cNx = {bib2, bib2, bib2, bib2};
        const f32x4v cN  = {bhn2, bhn2, bhn2, bhn2};

        hj = 0.0f;
        hzb[lane] = (_Float16)0.0f;

        // gx A-frag role: rows 0..7 fwd (t = 4c + tl), rows 8..15 bwd
        // (t = T-1-4c - tl, mirrored so C reg s == step s for both dirs).
        const bool fsel = (j15 < 8);
        const int  lb_a = (j15 >> 2) & 1;
        const int  tl_a = j15 & 3;
        const bool axv  = fsel ? (quad < 2) : (quad >= 2);

        unsigned int ypk[16];   // steps k<32, packed 2 f16/reg (static idx)

        // ---- park phase: chunks 0..7 (steps k=0..31) ----
        #pragma unroll
        for (int c = 0; c < 8; ++c) {
            const int trow = fsel ? (4 * c + tl_a) : (T - 1 - 4 * c - tl_a);
            const _Float16* abase = yb + lb_a * YSB + trow * YST;
            half8 alo = *(const half8*)(axv ? (abase + klo)      : (hzb + HZ_ZOFF));
            half8 ahi = *(const half8*)(axv ? (abase + 16 + klo) : (hzb + HZ_ZOFF));
            f32x4v c0 = __builtin_amdgcn_mfma_f32_16x16x32_f16(alo, bflo[0], cR, 0, 0, 0);
            f32x4v c1 = __builtin_amdgcn_mfma_f32_16x16x32_f16(alo, bflo[1], cZ, 0, 0, 0);
            f32x4v c2g = __builtin_amdgcn_mfma_f32_16x16x32_f16(alo, bflo[2], cNx, 0, 0, 0);
            c0  = __builtin_amdgcn_mfma_f32_16x16x32_f16(ahi, bfhi[0], c0, 0, 0, 0);
            c1  = __builtin_amdgcn_mfma_f32_16x16x32_f16(ahi, bfhi[1], c1, 0, 0, 0);
            c2g = __builtin_amdgcn_mfma_f32_16x16x32_f16(ahi, bfhi[2], c2g, 0, 0, 0);

            #pragma unroll
            for (int s = 0; s < 4; ++s) {
                half8 a = *(const half8*)aptr;
                f32x4v d0 = __builtin_amdgcn_mfma_f32_16x16x32_f16(a, whB[0], zC, 0, 0, 0);
                f32x4v d1 = __builtin_amdgcn_mfma_f32_16x16x32_f16(a, whB[1], zC, 0, 0, 0);
                f32x4v d2 = __builtin_amdgcn_mfma_f32_16x16x32_f16(a, whB[2], cN, 0, 0, 0);
                float av = c0[s] + d0[0];
                float bv = c1[s] + d1[0];
                float Er = fexp2(fminf(58.f, -av));
                float rg = frcp(1.0f + Er);
                float cc = fmaf(rg, d2[0], c2g[s]);
                float Ez = fexp2(fminf(58.f, -bv));
                float Ec = fexp2(fminf(63.f, cc));
                float num = fmaf(hj - Ez, Ec, hj + Ez);
                float den = (1.0f + Ec) * (1.0f + Ez);
                float hn = num * frcp(den);
                hj = hn;
                _Float16 hh = (_Float16)hn;
                hzb[lane] = hh;
                unsigned int hb16 = (unsigned int)__builtin_bit_cast(unsigned short, hh);
                if (s & 1) ypk[2 * c + (s >> 1)] |= hb16 << 16;
                else       ypk[2 * c + (s >> 1)]  = hb16;
            }
        }

        // ---- direct phase: chunks 8..15 (steps k=32..63), in-place writes ----
        {
            _Float16* yw = yb + lb * YSB + (isf ? 32 : 31) * YST + dir * H + j15;
            #pragma unroll 1
            for (int c = 8; c < 16; ++c) {
                const int trow = fsel ? (4 * c + tl_a) : (T - 1 - 4 * c - tl_a);
                const _Float16* abase = yb + lb_a * YSB + trow * YST;
                half8 alo = *(const half8*)(axv ? (abase + klo)      : (hzb + HZ_ZOFF));
                half8 ahi = *(const half8*)(axv ? (abase + 16 + klo) : (hzb + HZ_ZOFF));
                f32x4v c0 = __builtin_amdgcn_mfma_f32_16x16x32_f16(alo, bflo[0], cR, 0, 0, 0);
                f32x4v c1 = __builtin_amdgcn_mfma_f32_16x16x32_f16(alo, bflo[1], cZ, 0, 0, 0);
                f32x4v c2g = __builtin_amdgcn_mfma_f32_16x16x32_f16(alo, bflo[2], cNx, 0, 0, 0);
                c0  = __builtin_amdgcn_mfma_f32_16x16x32_f16(ahi, bfhi[0], c0, 0, 0, 0);
                c1  = __builtin_amdgcn_mfma_f32_16x16x32_f16(ahi, bfhi[1], c1, 0, 0, 0);
                c2g = __builtin_amdgcn_mfma_f32_16x16x32_f16(ahi, bfhi[2], c2g, 0, 0, 0);

                #pragma unroll
                for (int s = 0; s < 4; ++s) {
                    half8 a = *(const half8*)aptr;
                    f32x4v d0 = __builtin_amdgcn_mfma_f32_16x16x32_f16(a, whB[0], zC, 0, 0, 0);
                    f32x4v d1 = __builtin_amdgcn_mfma_f32_16x16x32_f16(a, whB[1], zC, 0, 0, 0);
                    f32x4v d2 = __builtin_amdgcn_mfma_f32_16x16x32_f16(a, whB[2], cN, 0, 0, 0);
                    float av = c0[s] + d0[0];
                    float bv = c1[s] + d1[0];
                    float Er = fexp2(fminf(58.f, -av));
                    float rg = frcp(1.0f + Er);
                    float cc = fmaf(rg, d2[0], c2g[s]);
                    float Ez = fexp2(fminf(58.f, -bv));
                    float Ec = fexp2(fminf(63.f, cc));
                    float num = fmaf(hj - Ez, Ec, hj + Ez);
                    float den = (1.0f + Ec) * (1.0f + Ez);
                    float hn = num * frcp(den);
                    hj = hn;
                    _Float16 hh = (_Float16)hn;
                    hzb[lane] = hh;
                    *yw = hh;
                    yw += ystep;
                }
            }
        }

        // ---- dump parked half (rows 0..31 fwd / 63..32 bwd) ----
        {
            _Float16* yw = yb + lb * YSB + (isf ? 0 : (T - 1)) * YST + dir * H + j15;
            #pragma unroll
            for (int i = 0; i < 16; ++i) {
                unsigned int v = ypk[i];
                *yw = __builtin_bit_cast(_Float16, (unsigned short)(v & 0xffffu));
                yw += ystep;
                *yw = __builtin_bit_cast(_Float16, (unsigned short)(v >> 16));
                yw += ystep;
            }
        }
    }

    // ================= classifier + softmax (final y in yb) =================
    #pragma unroll
    for (int i = 0; i < 2; ++i) {
        int idx = lane + i * 64;
        int bb  = idx >> 6;
        int t   = idx & 63;
        const _Float16* yrow = yb + bb * YSB + t * YST;
        float yv[D2];
        #pragma unroll
        for (int k8 = 0; k8 < 4; ++k8) {
            half8 v = *(const half8*)(yrow + k8 * 8);
            #pragma unroll
            for (int i8 = 0; i8 < 8; ++i8) yv[k8 * 8 + i8] = (float)v[i8];
        }
        float lg[NCLS];
        #pragma unroll
        for (int c = 0; c < NCLS; ++c) {
            const float* wc = Wc + c * D2;
            float acc = bc[c];
            #pragma unroll
            for (int k = 0; k < D2; ++k) acc = fmaf(wc[k], yv[k], acc);
            lg[c] = acc;
        }
        float m = fmaxf(fmaxf(lg[0], lg[1]), fmaxf(lg[2], lg[3]));
        float e0 = __expf(lg[0] - m), e1 = __expf(lg[1] - m);
        float e2 = __expf(lg[2] - m), e3 = __expf(lg[3] - m);
        float inv = frcp(e0 + e1 + e2 + e3);
        size_t bglob = (size_t)blockIdx.x * 2 + bb;
        float4 o;
        o.x = e0 * inv; o.y = e1 * inv; o.z = e2 * inv; o.w = e3 * inv;
        ((float4*)out)[bglob * T + t] = o;
    }
}

extern "C" void kernel_launch(void* const* d_in, const int* in_sizes, int n_in,
                              void* d_out, int out_size, void* d_ws, size_t ws_size,
                              hipStream_t stream) {
    const float* x   = (const float*)d_in[0];
    const float* Wi1 = (const float*)d_in[1];
    const float* Wh1 = (const float*)d_in[2];
    const float* bi1 = (const float*)d_in[3];
    const float* bh1 = (const float*)d_in[4];
    const float* Wi5 = (const float*)d_in[5];
    const float* Wh5 = (const float*)d_in[6];
    const float* bi5 = (const float*)d_in[7];
    const float* bh5 = (const float*)d_in[8];
    const float* Wc  = (const float*)d_in[9];
    const float* bc  = (const float*)d_in[10];
    float* out = (float*)d_out;

    const int B = in_sizes[0] / (T * F_IN);   // 16384
    dim3 grid(B / 2), block(64);
    hipLaunchKernelGGL(bigru_all, grid, block, 0, stream,
                       x, Wi1, Wh1, bi1, bh1, Wi5, Wh5, bi5, bh5, Wc, bc, out);
}